// Round 1
// baseline (582.068 us; speedup 1.0000x reference)
//
#include <hip/hip_runtime.h>
#include <hip/hip_bf16.h>
#include <cstddef>

#define ALPHA 0.2f
#define EPS 1e-8f

// ---------------------------------------------------------------------------
// K1: h = x @ W   (x: [N,128] f32, W: [128,128] f32, h: [N,128] f32)
// 32 nodes per block, 256 threads, 4x4 register tile per thread.
// ---------------------------------------------------------------------------
__global__ __launch_bounds__(256) void gemm_kernel(
    const float* __restrict__ x, const float* __restrict__ W,
    float* __restrict__ h, int n) {
  __shared__ float x_lds[128][36];   // [k][node], stride 36 floats -> 16B aligned
  __shared__ float w_lds[32][128];   // [kk][dim]

  const int t = threadIdx.x;
  const int node0 = blockIdx.x * 32;

  // stage x tile transposed: thread t loads 16 contiguous floats of one row
  {
    int node = t >> 3;             // 0..31
    int dbase = (t & 7) * 16;      // 0,16,...,112
    int nid = node0 + node;
    if (nid >= n) nid = n - 1;
    const float* xr = x + (size_t)nid * 128 + dbase;
    float4 v[4];
    v[0] = ((const float4*)xr)[0];
    v[1] = ((const float4*)xr)[1];
    v[2] = ((const float4*)xr)[2];
    v[3] = ((const float4*)xr)[3];
    const float* vs = (const float*)v;
#pragma unroll
    for (int j = 0; j < 16; j++) x_lds[dbase + j][node] = vs[j];
  }

  float acc[4][4];
#pragma unroll
  for (int j = 0; j < 4; j++)
#pragma unroll
    for (int i = 0; i < 4; i++) acc[j][i] = 0.f;

  const int tn = t >> 5;   // 0..7  (node group: nodes tn*4 .. tn*4+3)
  const int td = t & 31;   // 0..31 (dim group:  dims  td*4 .. td*4+3)

  for (int k0 = 0; k0 < 128; k0 += 32) {
    __syncthreads();
    // stage W rows k0..k0+31
    {
      int kk = t >> 3;             // 0..31
      int cb = (t & 7) * 16;       // 0..112
      const float* wr = W + (size_t)(k0 + kk) * 128 + cb;
      float4 w0 = ((const float4*)wr)[0];
      float4 w1 = ((const float4*)wr)[1];
      float4 w2 = ((const float4*)wr)[2];
      float4 w3 = ((const float4*)wr)[3];
      float4* dst = (float4*)&w_lds[kk][cb];
      dst[0] = w0; dst[1] = w1; dst[2] = w2; dst[3] = w3;
    }
    __syncthreads();
#pragma unroll
    for (int kk = 0; kk < 32; kk++) {
      float4 xa = *(const float4*)&x_lds[k0 + kk][tn * 4];
      float4 wb = *(const float4*)&w_lds[kk][td * 4];
      const float xs[4] = {xa.x, xa.y, xa.z, xa.w};
      const float ws[4] = {wb.x, wb.y, wb.z, wb.w};
#pragma unroll
      for (int j = 0; j < 4; j++)
#pragma unroll
        for (int i = 0; i < 4; i++) acc[j][i] += xs[j] * ws[i];
    }
  }

#pragma unroll
  for (int j = 0; j < 4; j++) {
    int nid = node0 + tn * 4 + j;
    if (nid < n) {
      float4 o = make_float4(acc[j][0], acc[j][1], acc[j][2], acc[j][3]);
      *(float4*)&h[(size_t)nid * 128 + td * 4] = o;
    }
  }
}

// ---------------------------------------------------------------------------
// K2: s_src[i] = h[i].a[0:128], s_dst[i] = h[i].a[128:256]  (one wave per node)
// ---------------------------------------------------------------------------
__global__ __launch_bounds__(256) void scores_kernel(
    const float* __restrict__ h, const float* __restrict__ a,
    float* __restrict__ s_src, float* __restrict__ s_dst, int n) {
  const int wave = threadIdx.x >> 6;
  const int lane = threadIdx.x & 63;
  const int i = blockIdx.x * 4 + wave;
  if (i >= n) return;
  const float* hi = h + (size_t)i * 128;
  float v0 = hi[lane], v1 = hi[lane + 64];
  float s0 = v0 * a[lane] + v1 * a[lane + 64];
  float s1 = v0 * a[128 + lane] + v1 * a[192 + lane];
#pragma unroll
  for (int off = 32; off >= 1; off >>= 1) {
    s0 += __shfl_xor(s0, off, 64);
    s1 += __shfl_xor(s1, off, 64);
  }
  if (lane == 0) { s_src[i] = s0; s_dst[i] = s1; }
}

// ---------------------------------------------------------------------------
// K3: histogram of row[] into counts[]
// ---------------------------------------------------------------------------
__global__ __launch_bounds__(256) void hist_kernel(
    const int* __restrict__ row, int* __restrict__ counts, int E) {
  int e = blockIdx.x * 256 + threadIdx.x;
  if (e < E) atomicAdd(&counts[row[e]], 1);
}

// ---------------------------------------------------------------------------
// K4: exclusive scan counts -> row_ptr (n+1) and cursor (n). Single block.
// ---------------------------------------------------------------------------
__global__ __launch_bounds__(1024) void scan_kernel(
    const int* __restrict__ counts, int* __restrict__ row_ptr,
    int* __restrict__ cursor, int n) {
  __shared__ int sdata[1024];
  __shared__ int s_base;
  const int t = threadIdx.x;
  if (t == 0) s_base = 0;
  __syncthreads();
  const int PER = 8;
  const int CHUNK = 1024 * PER;
  for (int base = 0; base < n; base += CHUNK) {
    int v[PER];
    int local = 0;
    int i0 = base + t * PER;
#pragma unroll
    for (int j = 0; j < PER; j++) {
      int idx = i0 + j;
      v[j] = (idx < n) ? counts[idx] : 0;
      local += v[j];
    }
    sdata[t] = local;
    __syncthreads();
    for (int off = 1; off < 1024; off <<= 1) {
      int y = (t >= off) ? sdata[t - off] : 0;
      __syncthreads();
      sdata[t] += y;
      __syncthreads();
    }
    int excl = sdata[t] - local;
    int total = sdata[1023];
    int run = s_base + excl;
#pragma unroll
    for (int j = 0; j < PER; j++) {
      int idx = i0 + j;
      if (idx < n) { row_ptr[idx] = run; cursor[idx] = run; }
      run += v[j];
    }
    __syncthreads();
    if (t == 0) s_base += total;
    __syncthreads();
  }
  if (t == 0) row_ptr[n] = s_base;
}

// ---------------------------------------------------------------------------
// K5: scatter edges into CSR order; compute e = leaky_relu(s_src[r]+s_dst[c])
// ---------------------------------------------------------------------------
__global__ __launch_bounds__(256) void scatter_kernel(
    const int* __restrict__ row, const int* __restrict__ col,
    const float* __restrict__ s_src, const float* __restrict__ s_dst,
    int* __restrict__ cursor, int* __restrict__ edge_col,
    float* __restrict__ edge_e, int E) {
  int e = blockIdx.x * 256 + threadIdx.x;
  if (e >= E) return;
  int r = row[e];
  int c = col[e];
  float ev = s_src[r] + s_dst[c];
  ev = ev > 0.f ? ev : ALPHA * ev;
  int pos = atomicAdd(&cursor[r], 1);
  edge_col[pos] = c;
  edge_e[pos] = ev;
}

// ---------------------------------------------------------------------------
// K6: per-row softmax + weighted gather of h[col] + ELU.  One wave per row.
// ---------------------------------------------------------------------------
__global__ __launch_bounds__(256) void attend_kernel(
    const float* __restrict__ h, const int* __restrict__ row_ptr,
    const int* __restrict__ edge_col, const float* __restrict__ edge_e,
    float* __restrict__ out, int n) {
  const int wave = threadIdx.x >> 6;
  const int lane = threadIdx.x & 63;
  const int r = blockIdx.x * 4 + wave;
  if (r >= n) return;
  const int start = row_ptr[r];
  const int deg = row_ptr[r + 1] - start;
  float acc0 = 0.f, acc1 = 0.f;
  if (deg > 0) {
    float m = -INFINITY;
    for (int j = lane; j < deg; j += 64) m = fmaxf(m, edge_e[start + j]);
#pragma unroll
    for (int off = 32; off >= 1; off >>= 1) m = fmaxf(m, __shfl_xor(m, off, 64));
    float s = 0.f;
    for (int j = lane; j < deg; j += 64) s += __expf(edge_e[start + j] - m);
#pragma unroll
    for (int off = 32; off >= 1; off >>= 1) s += __shfl_xor(s, off, 64);
    float inv = 1.0f / fmaxf(s, EPS);
    for (int j = 0; j < deg; j++) {
      float att = __expf(edge_e[start + j] - m) * inv;
      int c = edge_col[start + j];
      const float* hc = h + (size_t)c * 128;
      acc0 += att * hc[lane];
      acc1 += att * hc[lane + 64];
    }
  }
  out[(size_t)r * 128 + lane]      = acc0 > 0.f ? acc0 : expm1f(acc0);
  out[(size_t)r * 128 + lane + 64] = acc1 > 0.f ? acc1 : expm1f(acc1);
}

// ---------------------------------------------------------------------------
extern "C" void kernel_launch(void* const* d_in, const int* in_sizes, int n_in,
                              void* d_out, int out_size, void* d_ws, size_t ws_size,
                              hipStream_t stream) {
  const float* x   = (const float*)d_in[0];
  const int*   row = (const int*)d_in[1];
  const int*   col = (const int*)d_in[2];
  const float* W   = (const float*)d_in[3];
  const float* a   = (const float*)d_in[4];
  float* out = (float*)d_out;

  const int N = in_sizes[0] / 128;
  const int E = in_sizes[1];

  // workspace layout (all 4-byte types; h at offset 0 is 16B aligned)
  char* ws = (char*)d_ws;
  float* h        = (float*)ws;                          ws += (size_t)N * 128 * 4;
  float* s_src    = (float*)ws;                          ws += (size_t)N * 4;
  float* s_dst    = (float*)ws;                          ws += (size_t)N * 4;
  int*   counts   = (int*)ws;                            ws += (size_t)N * 4;
  int*   row_ptr  = (int*)ws;                            ws += (size_t)(N + 1) * 4;
  int*   cursor   = (int*)ws;                            ws += (size_t)N * 4;
  int*   edge_col = (int*)ws;                            ws += (size_t)E * 4;
  float* edge_e   = (float*)ws;                          ws += (size_t)E * 4;

  hipMemsetAsync(counts, 0, (size_t)N * 4, stream);

  dim3 blk(256);
  gemm_kernel<<<dim3((N + 31) / 32), blk, 0, stream>>>(x, W, h, N);
  scores_kernel<<<dim3((N + 3) / 4), blk, 0, stream>>>(h, a, s_src, s_dst, N);
  hist_kernel<<<dim3((E + 255) / 256), blk, 0, stream>>>(row, counts, E);
  scan_kernel<<<dim3(1), dim3(1024), 0, stream>>>(counts, row_ptr, cursor, N);
  scatter_kernel<<<dim3((E + 255) / 256), blk, 0, stream>>>(
      row, col, s_src, s_dst, cursor, edge_col, edge_e, E);
  attend_kernel<<<dim3((N + 3) / 4), blk, 0, stream>>>(
      h, row_ptr, edge_col, edge_e, out, N);
}

// Round 2
// 346.020 us; speedup vs baseline: 1.6822x; 1.6822x over previous
//
#include <hip/hip_runtime.h>
#include <cstddef>

#define ALPHA 0.2f
#define EPS 1e-8f

static __device__ __forceinline__ unsigned short f2bf(float f) {
  unsigned int u = __float_as_uint(f);
  unsigned int r = u + 0x7fffu + ((u >> 16) & 1u);
  return (unsigned short)(r >> 16);
}
static __device__ __forceinline__ float bf2f(unsigned short s) {
  return __uint_as_float(((unsigned int)s) << 16);
}

// ---------------------------------------------------------------------------
// K1: h = x @ W (f32 compute, bf16 store) + fused scores s_src/s_dst.
// 32 nodes per block, 256 threads, 4x4 register tile per thread.
// ---------------------------------------------------------------------------
__global__ __launch_bounds__(256) void gemm_scores_kernel(
    const float* __restrict__ x, const float* __restrict__ W,
    const float* __restrict__ a, unsigned short* __restrict__ h_bf,
    float* __restrict__ s_src, float* __restrict__ s_dst, int n) {
  __shared__ float x_lds[128][36];   // [k][node]
  __shared__ float w_lds[32][128];   // [kk][dim]

  const int t = threadIdx.x;
  const int node0 = blockIdx.x * 32;

  // stage x tile transposed
  {
    int node = t >> 3;             // 0..31
    int dbase = (t & 7) * 16;      // 0..112
    int nid = node0 + node;
    if (nid >= n) nid = n - 1;
    const float* xr = x + (size_t)nid * 128 + dbase;
    float4 v[4];
    v[0] = ((const float4*)xr)[0];
    v[1] = ((const float4*)xr)[1];
    v[2] = ((const float4*)xr)[2];
    v[3] = ((const float4*)xr)[3];
    const float* vs = (const float*)v;
#pragma unroll
    for (int j = 0; j < 16; j++) x_lds[dbase + j][node] = vs[j];
  }

  float acc[4][4];
#pragma unroll
  for (int j = 0; j < 4; j++)
#pragma unroll
    for (int i = 0; i < 4; i++) acc[j][i] = 0.f;

  const int tn = t >> 5;   // 0..7
  const int td = t & 31;   // 0..31

  for (int k0 = 0; k0 < 128; k0 += 32) {
    __syncthreads();
    {
      int kk = t >> 3;
      int cb = (t & 7) * 16;
      const float* wr = W + (size_t)(k0 + kk) * 128 + cb;
      float4 w0 = ((const float4*)wr)[0];
      float4 w1 = ((const float4*)wr)[1];
      float4 w2 = ((const float4*)wr)[2];
      float4 w3 = ((const float4*)wr)[3];
      float4* dst = (float4*)&w_lds[kk][cb];
      dst[0] = w0; dst[1] = w1; dst[2] = w2; dst[3] = w3;
    }
    __syncthreads();
#pragma unroll
    for (int kk = 0; kk < 32; kk++) {
      float4 xa = *(const float4*)&x_lds[k0 + kk][tn * 4];
      float4 wb = *(const float4*)&w_lds[kk][td * 4];
      const float xs[4] = {xa.x, xa.y, xa.z, xa.w};
      const float ws[4] = {wb.x, wb.y, wb.z, wb.w};
#pragma unroll
      for (int j = 0; j < 4; j++)
#pragma unroll
        for (int i = 0; i < 4; i++) acc[j][i] += xs[j] * ws[i];
    }
  }

  // epilogue: bf16 h store + fused scores
  float av0[4], av1[4];
#pragma unroll
  for (int i = 0; i < 4; i++) {
    av0[i] = a[td * 4 + i];
    av1[i] = a[128 + td * 4 + i];
  }
#pragma unroll
  for (int j = 0; j < 4; j++) {
    int nid = node0 + tn * 4 + j;
    bool valid = nid < n;
    if (valid) {
      ushort4 o;
      o.x = f2bf(acc[j][0]); o.y = f2bf(acc[j][1]);
      o.z = f2bf(acc[j][2]); o.w = f2bf(acc[j][3]);
      *(ushort4*)&h_bf[(size_t)nid * 128 + td * 4] = o;
    }
    float p0 = 0.f, p1 = 0.f;
#pragma unroll
    for (int i = 0; i < 4; i++) {
      p0 += acc[j][i] * av0[i];
      p1 += acc[j][i] * av1[i];
    }
#pragma unroll
    for (int off = 16; off >= 1; off >>= 1) {
      p0 += __shfl_xor(p0, off, 64);
      p1 += __shfl_xor(p1, off, 64);
    }
    if (td == 0 && valid) { s_src[nid] = p0; s_dst[nid] = p1; }
  }
}

// ---------------------------------------------------------------------------
// K2: histogram of row[] (4 edges/thread)
// ---------------------------------------------------------------------------
__global__ __launch_bounds__(256) void hist_kernel(
    const int* __restrict__ row, int* __restrict__ counts, int E) {
  int i = (blockIdx.x * 256 + threadIdx.x) * 4;
  if (i + 3 < E) {
    int4 v = *(const int4*)&row[i];
    atomicAdd(&counts[v.x], 1);
    atomicAdd(&counts[v.y], 1);
    atomicAdd(&counts[v.z], 1);
    atomicAdd(&counts[v.w], 1);
  } else {
    for (int j = 0; j < 4; j++)
      if (i + j < E) atomicAdd(&counts[row[i + j]], 1);
  }
}

// ---------------------------------------------------------------------------
// K3a: per-block (1024-elem) partial sums of counts
// ---------------------------------------------------------------------------
__global__ __launch_bounds__(256) void partial_kernel(
    const int* __restrict__ counts, int* __restrict__ partials, int n) {
  __shared__ int red[256];
  const int t = threadIdx.x;
  int base = blockIdx.x * 1024 + t * 4;
  int s = 0;
  if (base + 3 < n) {
    int4 v = *(const int4*)&counts[base];
    s = v.x + v.y + v.z + v.w;
  } else {
    for (int j = 0; j < 4; j++) if (base + j < n) s += counts[base + j];
  }
  red[t] = s;
  __syncthreads();
  for (int off = 128; off >= 1; off >>= 1) {
    if (t < off) red[t] += red[t + off];
    __syncthreads();
  }
  if (t == 0) partials[blockIdx.x] = red[0];
}

// ---------------------------------------------------------------------------
// K3b: exclusive scan of nb (<=128) partials; also writes row_ptr[n]=total
// ---------------------------------------------------------------------------
__global__ __launch_bounds__(128) void scanp_kernel(
    const int* __restrict__ partials, int* __restrict__ scanned,
    int* __restrict__ row_ptr, int nb, int n) {
  __shared__ int sd[128];
  const int t = threadIdx.x;
  int v = (t < nb) ? partials[t] : 0;
  sd[t] = v;
  __syncthreads();
  for (int off = 1; off < 128; off <<= 1) {
    int y = (t >= off) ? sd[t - off] : 0;
    __syncthreads();
    sd[t] += y;
    __syncthreads();
  }
  if (t < nb) scanned[t] = sd[t] - v;
  if (t == 127) row_ptr[n] = sd[127];
}

// ---------------------------------------------------------------------------
// K3c: row_ptr / cursor from counts + scanned block bases
// ---------------------------------------------------------------------------
__global__ __launch_bounds__(256) void rowptr_kernel(
    const int* __restrict__ counts, const int* __restrict__ scanned,
    int* __restrict__ row_ptr, int* __restrict__ cursor, int n) {
  __shared__ int red[256];
  const int t = threadIdx.x;
  int base = blockIdx.x * 1024 + t * 4;
  int v[4];
  int s = 0;
  if (base + 3 < n) {
    int4 q = *(const int4*)&counts[base];
    v[0] = q.x; v[1] = q.y; v[2] = q.z; v[3] = q.w;
  } else {
    for (int j = 0; j < 4; j++) v[j] = (base + j < n) ? counts[base + j] : 0;
  }
  s = v[0] + v[1] + v[2] + v[3];
  red[t] = s;
  __syncthreads();
  for (int off = 1; off < 256; off <<= 1) {
    int y = (t >= off) ? red[t - off] : 0;
    __syncthreads();
    red[t] += y;
    __syncthreads();
  }
  int run = scanned[blockIdx.x] + red[t] - s;
#pragma unroll
  for (int j = 0; j < 4; j++) {
    if (base + j < n) { row_ptr[base + j] = run; cursor[base + j] = run; }
    run += v[j];
  }
}

// ---------------------------------------------------------------------------
// K4: scatter edges into CSR order; e = leaky_relu(s_src[r]+s_dst[c])
// ---------------------------------------------------------------------------
__global__ __launch_bounds__(256) void scatter_kernel(
    const int* __restrict__ row, const int* __restrict__ col,
    const float* __restrict__ s_src, const float* __restrict__ s_dst,
    int* __restrict__ cursor, int* __restrict__ edge_col,
    float* __restrict__ edge_e, int E) {
  int e = blockIdx.x * 256 + threadIdx.x;
  if (e >= E) return;
  int r = row[e];
  int c = col[e];
  float ev = s_src[r] + s_dst[c];
  ev = ev > 0.f ? ev : ALPHA * ev;
  int pos = atomicAdd(&cursor[r], 1);
  edge_col[pos] = c;
  edge_e[pos] = ev;
}

// ---------------------------------------------------------------------------
// K5: per-row softmax + weighted bf16 gather of h[col] + ELU. One wave/row.
// ---------------------------------------------------------------------------
__global__ __launch_bounds__(256) void attend_kernel(
    const ushort2* __restrict__ h2, const int* __restrict__ row_ptr,
    const int* __restrict__ edge_col, const float* __restrict__ edge_e,
    float* __restrict__ out, int n) {
  const int wave = threadIdx.x >> 6;
  const int lane = threadIdx.x & 63;
  const int r = blockIdx.x * 4 + wave;
  if (r >= n) return;
  const int start = row_ptr[r];
  const int deg = row_ptr[r + 1] - start;
  float acc0 = 0.f, acc1 = 0.f;
  if (deg > 0) {
    float m = -INFINITY;
    for (int j = lane; j < deg; j += 64) m = fmaxf(m, edge_e[start + j]);
#pragma unroll
    for (int off = 32; off >= 1; off >>= 1) m = fmaxf(m, __shfl_xor(m, off, 64));
    float s = 0.f;
    for (int j = lane; j < deg; j += 64) s += __expf(edge_e[start + j] - m);
#pragma unroll
    for (int off = 32; off >= 1; off >>= 1) s += __shfl_xor(s, off, 64);
    float inv = 1.0f / fmaxf(s, EPS);
    int j = 0;
    for (; j + 2 <= deg; j += 2) {
      int c0 = edge_col[start + j];
      int c1 = edge_col[start + j + 1];
      float e0 = edge_e[start + j];
      float e1 = edge_e[start + j + 1];
      ushort2 v0 = h2[(size_t)c0 * 64 + lane];
      ushort2 v1 = h2[(size_t)c1 * 64 + lane];
      float a0 = __expf(e0 - m) * inv;
      float a1 = __expf(e1 - m) * inv;
      acc0 += a0 * bf2f(v0.x) + a1 * bf2f(v1.x);
      acc1 += a0 * bf2f(v0.y) + a1 * bf2f(v1.y);
    }
    if (j < deg) {
      int c0 = edge_col[start + j];
      float e0 = edge_e[start + j];
      ushort2 v0 = h2[(size_t)c0 * 64 + lane];
      float a0 = __expf(e0 - m) * inv;
      acc0 += a0 * bf2f(v0.x);
      acc1 += a0 * bf2f(v0.y);
    }
  }
  float o0 = acc0 > 0.f ? acc0 : expm1f(acc0);
  float o1 = acc1 > 0.f ? acc1 : expm1f(acc1);
  *(float2*)&out[(size_t)r * 128 + lane * 2] = make_float2(o0, o1);
}

// ---------------------------------------------------------------------------
static inline size_t align256(size_t v) { return (v + 255) & ~(size_t)255; }

extern "C" void kernel_launch(void* const* d_in, const int* in_sizes, int n_in,
                              void* d_out, int out_size, void* d_ws, size_t ws_size,
                              hipStream_t stream) {
  const float* x   = (const float*)d_in[0];
  const int*   row = (const int*)d_in[1];
  const int*   col = (const int*)d_in[2];
  const float* W   = (const float*)d_in[3];
  const float* a   = (const float*)d_in[4];
  float* out = (float*)d_out;

  const int N = in_sizes[0] / 128;
  const int E = in_sizes[1];
  const int NB = (N + 1023) / 1024;   // 98 for N=100000 (must be <=128)

  char* ws = (char*)d_ws;
  unsigned short* h_bf = (unsigned short*)ws; ws += align256((size_t)N * 128 * 2);
  float* s_src    = (float*)ws;  ws += align256((size_t)N * 4);
  float* s_dst    = (float*)ws;  ws += align256((size_t)N * 4);
  int*   counts   = (int*)ws;    ws += align256((size_t)N * 4);
  int*   row_ptr  = (int*)ws;    ws += align256((size_t)(N + 1) * 4);
  int*   cursor   = (int*)ws;    ws += align256((size_t)N * 4);
  int*   edge_col = (int*)ws;    ws += align256((size_t)E * 4);
  float* edge_e   = (float*)ws;  ws += align256((size_t)E * 4);
  int*   partials = (int*)ws;    ws += align256(1024 * 4);
  int*   scanned  = (int*)ws;    ws += align256(1024 * 4);

  hipMemsetAsync(counts, 0, (size_t)N * 4, stream);

  dim3 blk(256);
  gemm_scores_kernel<<<dim3((N + 31) / 32), blk, 0, stream>>>(
      x, W, a, h_bf, s_src, s_dst, N);
  hist_kernel<<<dim3((E + 1023) / 1024), blk, 0, stream>>>(row, counts, E);
  partial_kernel<<<dim3(NB), blk, 0, stream>>>(counts, partials, N);
  scanp_kernel<<<dim3(1), dim3(128), 0, stream>>>(partials, scanned, row_ptr, NB, N);
  rowptr_kernel<<<dim3(NB), blk, 0, stream>>>(counts, scanned, row_ptr, cursor, N);
  scatter_kernel<<<dim3((E + 255) / 256), blk, 0, stream>>>(
      row, col, s_src, s_dst, cursor, edge_col, edge_e, E);
  attend_kernel<<<dim3((N + 3) / 4), blk, 0, stream>>>(
      (const ushort2*)h_bf, row_ptr, edge_col, edge_e, out, N);
}

// Round 3
// 336.814 us; speedup vs baseline: 1.7282x; 1.0273x over previous
//
#include <hip/hip_runtime.h>
#include <cstddef>

#define ALPHA 0.2f
#define EPS 1e-8f

static __device__ __forceinline__ unsigned short f2bf(float f) {
  unsigned int u = __float_as_uint(f);
  unsigned int r = u + 0x7fffu + ((u >> 16) & 1u);
  return (unsigned short)(r >> 16);
}
static __device__ __forceinline__ float bf2f(unsigned short s) {
  return __uint_as_float(((unsigned int)s) << 16);
}
static __device__ __forceinline__ float rlanef(float v, int l) {
  return __uint_as_float(__builtin_amdgcn_readlane(__float_as_uint(v), l));
}

// ---------------------------------------------------------------------------
// K1: h = x @ W (f32 compute, bf16 store) + fused scores s_src/s_dst.
// ---------------------------------------------------------------------------
__global__ __launch_bounds__(256) void gemm_scores_kernel(
    const float* __restrict__ x, const float* __restrict__ W,
    const float* __restrict__ a, unsigned short* __restrict__ h_bf,
    float* __restrict__ s_src, float* __restrict__ s_dst, int n) {
  __shared__ float x_lds[128][36];   // [k][node]
  __shared__ float w_lds[32][128];   // [kk][dim]

  const int t = threadIdx.x;
  const int node0 = blockIdx.x * 32;

  {
    int node = t >> 3;
    int dbase = (t & 7) * 16;
    int nid = node0 + node;
    if (nid >= n) nid = n - 1;
    const float* xr = x + (size_t)nid * 128 + dbase;
    float4 v[4];
    v[0] = ((const float4*)xr)[0];
    v[1] = ((const float4*)xr)[1];
    v[2] = ((const float4*)xr)[2];
    v[3] = ((const float4*)xr)[3];
    const float* vs = (const float*)v;
#pragma unroll
    for (int j = 0; j < 16; j++) x_lds[dbase + j][node] = vs[j];
  }

  float acc[4][4];
#pragma unroll
  for (int j = 0; j < 4; j++)
#pragma unroll
    for (int i = 0; i < 4; i++) acc[j][i] = 0.f;

  const int tn = t >> 5;
  const int td = t & 31;

  for (int k0 = 0; k0 < 128; k0 += 32) {
    __syncthreads();
    {
      int kk = t >> 3;
      int cb = (t & 7) * 16;
      const float* wr = W + (size_t)(k0 + kk) * 128 + cb;
      float4 w0 = ((const float4*)wr)[0];
      float4 w1 = ((const float4*)wr)[1];
      float4 w2 = ((const float4*)wr)[2];
      float4 w3 = ((const float4*)wr)[3];
      float4* dst = (float4*)&w_lds[kk][cb];
      dst[0] = w0; dst[1] = w1; dst[2] = w2; dst[3] = w3;
    }
    __syncthreads();
#pragma unroll
    for (int kk = 0; kk < 32; kk++) {
      float4 xa = *(const float4*)&x_lds[k0 + kk][tn * 4];
      float4 wb = *(const float4*)&w_lds[kk][td * 4];
      const float xs[4] = {xa.x, xa.y, xa.z, xa.w};
      const float ws[4] = {wb.x, wb.y, wb.z, wb.w};
#pragma unroll
      for (int j = 0; j < 4; j++)
#pragma unroll
        for (int i = 0; i < 4; i++) acc[j][i] += xs[j] * ws[i];
    }
  }

  float av0[4], av1[4];
#pragma unroll
  for (int i = 0; i < 4; i++) {
    av0[i] = a[td * 4 + i];
    av1[i] = a[128 + td * 4 + i];
  }
#pragma unroll
  for (int j = 0; j < 4; j++) {
    int nid = node0 + tn * 4 + j;
    bool valid = nid < n;
    if (valid) {
      ushort4 o;
      o.x = f2bf(acc[j][0]); o.y = f2bf(acc[j][1]);
      o.z = f2bf(acc[j][2]); o.w = f2bf(acc[j][3]);
      *(ushort4*)&h_bf[(size_t)nid * 128 + td * 4] = o;
    }
    float p0 = 0.f, p1 = 0.f;
#pragma unroll
    for (int i = 0; i < 4; i++) {
      p0 += acc[j][i] * av0[i];
      p1 += acc[j][i] * av1[i];
    }
#pragma unroll
    for (int off = 16; off >= 1; off >>= 1) {
      p0 += __shfl_xor(p0, off, 64);
      p1 += __shfl_xor(p1, off, 64);
    }
    if (td == 0 && valid) { s_src[nid] = p0; s_dst[nid] = p1; }
  }
}

// ---------------------------------------------------------------------------
// K2: histogram of row[] (4 edges/thread)
// ---------------------------------------------------------------------------
__global__ __launch_bounds__(256) void hist_kernel(
    const int* __restrict__ row, int* __restrict__ counts, int E) {
  int i = (blockIdx.x * 256 + threadIdx.x) * 4;
  if (i + 3 < E) {
    int4 v = *(const int4*)&row[i];
    atomicAdd(&counts[v.x], 1);
    atomicAdd(&counts[v.y], 1);
    atomicAdd(&counts[v.z], 1);
    atomicAdd(&counts[v.w], 1);
  } else {
    for (int j = 0; j < 4; j++)
      if (i + j < E) atomicAdd(&counts[row[i + j]], 1);
  }
}

// ---------------------------------------------------------------------------
// K3a: per-block (1024-elem) partial sums of counts
// ---------------------------------------------------------------------------
__global__ __launch_bounds__(256) void partial_kernel(
    const int* __restrict__ counts, int* __restrict__ partials, int n) {
  __shared__ int red[256];
  const int t = threadIdx.x;
  int base = blockIdx.x * 1024 + t * 4;
  int s = 0;
  if (base + 3 < n) {
    int4 v = *(const int4*)&counts[base];
    s = v.x + v.y + v.z + v.w;
  } else {
    for (int j = 0; j < 4; j++) if (base + j < n) s += counts[base + j];
  }
  red[t] = s;
  __syncthreads();
  for (int off = 128; off >= 1; off >>= 1) {
    if (t < off) red[t] += red[t + off];
    __syncthreads();
  }
  if (t == 0) partials[blockIdx.x] = red[0];
}

// ---------------------------------------------------------------------------
// K3b: exclusive scan of nb (<=128) partials; writes row_ptr[n]=total
// ---------------------------------------------------------------------------
__global__ __launch_bounds__(128) void scanp_kernel(
    const int* __restrict__ partials, int* __restrict__ scanned,
    int* __restrict__ row_ptr, int nb, int n) {
  __shared__ int sd[128];
  const int t = threadIdx.x;
  int v = (t < nb) ? partials[t] : 0;
  sd[t] = v;
  __syncthreads();
  for (int off = 1; off < 128; off <<= 1) {
    int y = (t >= off) ? sd[t - off] : 0;
    __syncthreads();
    sd[t] += y;
    __syncthreads();
  }
  if (t < nb) scanned[t] = sd[t] - v;
  if (t == 127) row_ptr[n] = sd[127];
}

// ---------------------------------------------------------------------------
// K3c: row_ptr / cursor from counts + scanned block bases
// ---------------------------------------------------------------------------
__global__ __launch_bounds__(256) void rowptr_kernel(
    const int* __restrict__ counts, const int* __restrict__ scanned,
    int* __restrict__ row_ptr, int* __restrict__ cursor, int n) {
  __shared__ int red[256];
  const int t = threadIdx.x;
  int base = blockIdx.x * 1024 + t * 4;
  int v[4];
  int s = 0;
  if (base + 3 < n) {
    int4 q = *(const int4*)&counts[base];
    v[0] = q.x; v[1] = q.y; v[2] = q.z; v[3] = q.w;
  } else {
    for (int j = 0; j < 4; j++) v[j] = (base + j < n) ? counts[base + j] : 0;
  }
  s = v[0] + v[1] + v[2] + v[3];
  red[t] = s;
  __syncthreads();
  for (int off = 1; off < 256; off <<= 1) {
    int y = (t >= off) ? red[t - off] : 0;
    __syncthreads();
    red[t] += y;
    __syncthreads();
  }
  int run = scanned[blockIdx.x] + red[t] - s;
#pragma unroll
  for (int j = 0; j < 4; j++) {
    if (base + j < n) { row_ptr[base + j] = run; cursor[base + j] = run; }
    run += v[j];
  }
}

// ---------------------------------------------------------------------------
// K4: scatter edge cols into CSR order (4 edges/thread)
// ---------------------------------------------------------------------------
__global__ __launch_bounds__(256) void scatter_kernel(
    const int* __restrict__ row, const int* __restrict__ col,
    int* __restrict__ cursor, int* __restrict__ edge_col, int E) {
  int i = (blockIdx.x * 256 + threadIdx.x) * 4;
  if (i + 3 < E) {
    int4 rv = *(const int4*)&row[i];
    int4 cv = *(const int4*)&col[i];
    int p0 = atomicAdd(&cursor[rv.x], 1); edge_col[p0] = cv.x;
    int p1 = atomicAdd(&cursor[rv.y], 1); edge_col[p1] = cv.y;
    int p2 = atomicAdd(&cursor[rv.z], 1); edge_col[p2] = cv.z;
    int p3 = atomicAdd(&cursor[rv.w], 1); edge_col[p3] = cv.w;
  } else {
    for (int j = 0; j < 4; j++) {
      if (i + j < E) {
        int r = row[i + j];
        int c = col[i + j];
        int p = atomicAdd(&cursor[r], 1);
        edge_col[p] = c;
      }
    }
  }
}

// ---------------------------------------------------------------------------
// K5: lane-per-edge online softmax + weighted bf16 gather + ELU. 1 wave/row.
// e_j computed in-register from s_src[r] + s_dst[c_j]; exp once per edge.
// ---------------------------------------------------------------------------
__global__ __launch_bounds__(256) void attend_kernel(
    const ushort2* __restrict__ h2, const int* __restrict__ row_ptr,
    const int* __restrict__ edge_col, const float* __restrict__ s_src,
    const float* __restrict__ s_dst, float* __restrict__ out, int n) {
  const int wave = threadIdx.x >> 6;
  const int lane = threadIdx.x & 63;
  const int r = blockIdx.x * 4 + wave;
  if (r >= n) return;
  const int start = row_ptr[r];
  const int deg = row_ptr[r + 1] - start;
  float acc0 = 0.f, acc1 = 0.f;
  float m = -INFINITY, ssum = 0.f;
  const float sr = s_src[r];

  for (int base = 0; base < deg; base += 64) {
    const int rem = deg - base;            // > 0
    const bool act = lane < rem;
    int c = act ? edge_col[start + base + lane] : 0;
    float e = -INFINITY;
    if (act) {
      float ev = sr + s_dst[c];
      e = ev > 0.f ? ev : ALPHA * ev;
    }
    // chunk max
    float cm = e;
#pragma unroll
    for (int off = 32; off >= 1; off >>= 1) cm = fmaxf(cm, __shfl_xor(cm, off, 64));
    float m_new = fmaxf(m, cm);
    float scale = __expf(m - m_new);       // first chunk: exp(-inf)=0, accs are 0
    acc0 *= scale; acc1 *= scale; ssum *= scale;
    m = m_new;
    float p = act ? __expf(e - m) : 0.f;
    float cs = p;
#pragma unroll
    for (int off = 32; off >= 1; off >>= 1) cs += __shfl_xor(cs, off, 64);
    ssum += cs;
    // apply (unnormalized): readlane-broadcast p_k, c_k; gather h[c_k]
    const int cnt = rem < 64 ? rem : 64;
    int k = 0;
    for (; k + 4 <= cnt; k += 4) {
      float p0 = rlanef(p, k),     p1 = rlanef(p, k + 1);
      float p2 = rlanef(p, k + 2), p3 = rlanef(p, k + 3);
      int c0 = __builtin_amdgcn_readlane(c, k);
      int c1 = __builtin_amdgcn_readlane(c, k + 1);
      int c2 = __builtin_amdgcn_readlane(c, k + 2);
      int c3 = __builtin_amdgcn_readlane(c, k + 3);
      ushort2 v0 = h2[(size_t)c0 * 64 + lane];
      ushort2 v1 = h2[(size_t)c1 * 64 + lane];
      ushort2 v2 = h2[(size_t)c2 * 64 + lane];
      ushort2 v3 = h2[(size_t)c3 * 64 + lane];
      acc0 += p0 * bf2f(v0.x) + p1 * bf2f(v1.x) + p2 * bf2f(v2.x) + p3 * bf2f(v3.x);
      acc1 += p0 * bf2f(v0.y) + p1 * bf2f(v1.y) + p2 * bf2f(v2.y) + p3 * bf2f(v3.y);
    }
    for (; k < cnt; ++k) {
      float pk = rlanef(p, k);
      int ck = __builtin_amdgcn_readlane(c, k);
      ushort2 v = h2[(size_t)ck * 64 + lane];
      acc0 += pk * bf2f(v.x);
      acc1 += pk * bf2f(v.y);
    }
  }

  float inv = 1.0f / fmaxf(ssum, EPS);
  acc0 *= inv; acc1 *= inv;
  float o0 = acc0 > 0.f ? acc0 : expm1f(acc0);
  float o1 = acc1 > 0.f ? acc1 : expm1f(acc1);
  *(float2*)&out[(size_t)r * 128 + lane * 2] = make_float2(o0, o1);
}

// ---------------------------------------------------------------------------
static inline size_t align256(size_t v) { return (v + 255) & ~(size_t)255; }

extern "C" void kernel_launch(void* const* d_in, const int* in_sizes, int n_in,
                              void* d_out, int out_size, void* d_ws, size_t ws_size,
                              hipStream_t stream) {
  const float* x   = (const float*)d_in[0];
  const int*   row = (const int*)d_in[1];
  const int*   col = (const int*)d_in[2];
  const float* W   = (const float*)d_in[3];
  const float* a   = (const float*)d_in[4];
  float* out = (float*)d_out;

  const int N = in_sizes[0] / 128;
  const int E = in_sizes[1];
  const int NB = (N + 1023) / 1024;   // must be <=128

  char* ws = (char*)d_ws;
  unsigned short* h_bf = (unsigned short*)ws; ws += align256((size_t)N * 128 * 2);
  float* s_src    = (float*)ws;  ws += align256((size_t)N * 4);
  float* s_dst    = (float*)ws;  ws += align256((size_t)N * 4);
  int*   counts   = (int*)ws;    ws += align256((size_t)N * 4);
  int*   row_ptr  = (int*)ws;    ws += align256((size_t)(N + 1) * 4);
  int*   cursor   = (int*)ws;    ws += align256((size_t)N * 4);
  int*   edge_col = (int*)ws;    ws += align256((size_t)E * 4);
  int*   partials = (int*)ws;    ws += align256(1024 * 4);
  int*   scanned  = (int*)ws;    ws += align256(1024 * 4);

  hipMemsetAsync(counts, 0, (size_t)N * 4, stream);

  dim3 blk(256);
  gemm_scores_kernel<<<dim3((N + 31) / 32), blk, 0, stream>>>(
      x, W, a, h_bf, s_src, s_dst, N);
  hist_kernel<<<dim3((E + 1023) / 1024), blk, 0, stream>>>(row, counts, E);
  partial_kernel<<<dim3(NB), blk, 0, stream>>>(counts, partials, N);
  scanp_kernel<<<dim3(1), dim3(128), 0, stream>>>(partials, scanned, row_ptr, NB, N);
  rowptr_kernel<<<dim3(NB), blk, 0, stream>>>(counts, scanned, row_ptr, cursor, N);
  scatter_kernel<<<dim3((E + 1023) / 1024), blk, 0, stream>>>(
      row, col, cursor, edge_col, E);
  attend_kernel<<<dim3((N + 3) / 4), blk, 0, stream>>>(
      (const ushort2*)h_bf, row_ptr, edge_col, s_src, s_dst, out, N);
}

// Round 4
// 188.255 us; speedup vs baseline: 3.0919x; 1.7891x over previous
//
#include <hip/hip_runtime.h>
#include <cstddef>

#define ALPHA 0.2f
#define EPS 1e-8f
#define LOG_RPB 7                 // 128 rows per bin
#define RPB 128
#define COL_BITS 17               // N=100000 < 2^17
#define COL_MASK 0x1FFFFu
#define CAP 4096                  // max edges per bin handled in LDS (avg ~2048)

static __device__ __forceinline__ unsigned short f2bf(float f) {
  unsigned int u = __float_as_uint(f);
  unsigned int r = u + 0x7fffu + ((u >> 16) & 1u);
  return (unsigned short)(r >> 16);
}
static __device__ __forceinline__ float bf2f(unsigned short s) {
  return __uint_as_float(((unsigned int)s) << 16);
}
static __device__ __forceinline__ float rlanef(float v, int l) {
  return __uint_as_float(__builtin_amdgcn_readlane(__float_as_uint(v), l));
}

// ---------------------------------------------------------------------------
// K1: h = x @ W (f32 compute, bf16 store) + fused scores s_src/s_dst.
// ---------------------------------------------------------------------------
__global__ __launch_bounds__(256) void gemm_scores_kernel(
    const float* __restrict__ x, const float* __restrict__ W,
    const float* __restrict__ a, unsigned short* __restrict__ h_bf,
    float* __restrict__ s_src, float* __restrict__ s_dst, int n) {
  __shared__ float x_lds[128][36];
  __shared__ float w_lds[32][128];

  const int t = threadIdx.x;
  const int node0 = blockIdx.x * 32;

  {
    int node = t >> 3;
    int dbase = (t & 7) * 16;
    int nid = node0 + node;
    if (nid >= n) nid = n - 1;
    const float* xr = x + (size_t)nid * 128 + dbase;
    float4 v[4];
    v[0] = ((const float4*)xr)[0];
    v[1] = ((const float4*)xr)[1];
    v[2] = ((const float4*)xr)[2];
    v[3] = ((const float4*)xr)[3];
    const float* vs = (const float*)v;
#pragma unroll
    for (int j = 0; j < 16; j++) x_lds[dbase + j][node] = vs[j];
  }

  float acc[4][4];
#pragma unroll
  for (int j = 0; j < 4; j++)
#pragma unroll
    for (int i = 0; i < 4; i++) acc[j][i] = 0.f;

  const int tn = t >> 5;
  const int td = t & 31;

  for (int k0 = 0; k0 < 128; k0 += 32) {
    __syncthreads();
    {
      int kk = t >> 3;
      int cb = (t & 7) * 16;
      const float* wr = W + (size_t)(k0 + kk) * 128 + cb;
      float4 w0 = ((const float4*)wr)[0];
      float4 w1 = ((const float4*)wr)[1];
      float4 w2 = ((const float4*)wr)[2];
      float4 w3 = ((const float4*)wr)[3];
      float4* dst = (float4*)&w_lds[kk][cb];
      dst[0] = w0; dst[1] = w1; dst[2] = w2; dst[3] = w3;
    }
    __syncthreads();
#pragma unroll
    for (int kk = 0; kk < 32; kk++) {
      float4 xa = *(const float4*)&x_lds[k0 + kk][tn * 4];
      float4 wb = *(const float4*)&w_lds[kk][td * 4];
      const float xs[4] = {xa.x, xa.y, xa.z, xa.w};
      const float ws[4] = {wb.x, wb.y, wb.z, wb.w};
#pragma unroll
      for (int j = 0; j < 4; j++)
#pragma unroll
        for (int i = 0; i < 4; i++) acc[j][i] += xs[j] * ws[i];
    }
  }

  float av0[4], av1[4];
#pragma unroll
  for (int i = 0; i < 4; i++) {
    av0[i] = a[td * 4 + i];
    av1[i] = a[128 + td * 4 + i];
  }
#pragma unroll
  for (int j = 0; j < 4; j++) {
    int nid = node0 + tn * 4 + j;
    bool valid = nid < n;
    if (valid) {
      ushort4 o;
      o.x = f2bf(acc[j][0]); o.y = f2bf(acc[j][1]);
      o.z = f2bf(acc[j][2]); o.w = f2bf(acc[j][3]);
      *(ushort4*)&h_bf[(size_t)nid * 128 + td * 4] = o;
    }
    float p0 = 0.f, p1 = 0.f;
#pragma unroll
    for (int i = 0; i < 4; i++) {
      p0 += acc[j][i] * av0[i];
      p1 += acc[j][i] * av1[i];
    }
#pragma unroll
    for (int off = 16; off >= 1; off >>= 1) {
      p0 += __shfl_xor(p0, off, 64);
      p1 += __shfl_xor(p1, off, 64);
    }
    if (td == 0 && valid) { s_src[nid] = p0; s_dst[nid] = p1; }
  }
}

// ---------------------------------------------------------------------------
// K2: per-bin histogram (LDS-aggregated)
// ---------------------------------------------------------------------------
__global__ __launch_bounds__(256) void binhist_kernel(
    const int* __restrict__ row, int* __restrict__ bin_count, int E, int nbin) {
  __shared__ int hist[1024];
  for (int b = threadIdx.x; b < nbin; b += 256) hist[b] = 0;
  __syncthreads();
  int i0 = (blockIdx.x * 256 + threadIdx.x) * 4;
  const int stride = gridDim.x * 1024;
  for (int i = i0; i < E; i += stride) {
    if (i + 3 < E) {
      int4 v = *(const int4*)&row[i];
      atomicAdd(&hist[v.x >> LOG_RPB], 1);
      atomicAdd(&hist[v.y >> LOG_RPB], 1);
      atomicAdd(&hist[v.z >> LOG_RPB], 1);
      atomicAdd(&hist[v.w >> LOG_RPB], 1);
    } else {
      for (int j = 0; j < 4; j++)
        if (i + j < E) atomicAdd(&hist[row[i + j] >> LOG_RPB], 1);
    }
  }
  __syncthreads();
  for (int b = threadIdx.x; b < nbin; b += 256)
    if (hist[b]) atomicAdd(&bin_count[b], hist[b]);
}

// ---------------------------------------------------------------------------
// K3: exclusive scan of bin_count -> bin_start (nbin+1) and bin_cursor.
// Single block, 256 threads, up to 1024 bins.
// ---------------------------------------------------------------------------
__global__ __launch_bounds__(256) void binscan_kernel(
    const int* __restrict__ bin_count, int* __restrict__ bin_start,
    int* __restrict__ bin_cursor, int nbin) {
  __shared__ int part[256];
  const int t = threadIdx.x;
  int v[4];
  int s = 0;
#pragma unroll
  for (int j = 0; j < 4; j++) {
    int idx = t * 4 + j;
    v[j] = (idx < nbin) ? bin_count[idx] : 0;
    s += v[j];
  }
  part[t] = s;
  __syncthreads();
  for (int off = 1; off < 256; off <<= 1) {
    int y = (t >= off) ? part[t - off] : 0;
    __syncthreads();
    part[t] += y;
    __syncthreads();
  }
  int run = part[t] - s;
#pragma unroll
  for (int j = 0; j < 4; j++) {
    int idx = t * 4 + j;
    if (idx < nbin) { bin_start[idx] = run; bin_cursor[idx] = run; }
    run += v[j];
  }
  if (t == 255) bin_start[nbin] = part[255];
}

// ---------------------------------------------------------------------------
// K4: bin-scatter edges as packed (localrow<<17)|col, block-aggregated claims.
// 256 threads x 16 edges = 4096 edges/block.
// ---------------------------------------------------------------------------
__global__ __launch_bounds__(256) void binscatter_kernel(
    const int* __restrict__ row, const int* __restrict__ col,
    int* __restrict__ bin_cursor, unsigned int* __restrict__ packed,
    int E, int nbin) {
  __shared__ int hist[1024];
  __shared__ int base[1024];
  const int t = threadIdx.x;
  for (int b = t; b < nbin; b += 256) hist[b] = 0;
  __syncthreads();

  const int e0 = blockIdx.x * 4096;
  int r[16], c[16];
#pragma unroll
  for (int k = 0; k < 16; k++) {
    int idx = e0 + k * 256 + t;
    if (idx < E) {
      r[k] = row[idx];
      c[k] = col[idx];
      atomicAdd(&hist[r[k] >> LOG_RPB], 1);
    } else {
      r[k] = -1;
    }
  }
  __syncthreads();
  for (int b = t; b < nbin; b += 256) {
    int cnt = hist[b];
    base[b] = cnt ? atomicAdd(&bin_cursor[b], cnt) : 0;
  }
  __syncthreads();
#pragma unroll
  for (int k = 0; k < 16; k++) {
    if (r[k] >= 0) {
      int bin = r[k] >> LOG_RPB;
      int pos = atomicAdd(&base[bin], 1);
      packed[pos] = ((unsigned int)(r[k] & (RPB - 1)) << COL_BITS) |
                    ((unsigned int)c[k] & COL_MASK);
    }
  }
}

// ---------------------------------------------------------------------------
// K5: per-bin in-LDS counting sort + online-softmax attend + ELU.
// One 512-thread block (8 waves) per bin; each wave owns 16 rows.
// ---------------------------------------------------------------------------
__global__ __launch_bounds__(512) void attend_bin_kernel(
    const ushort2* __restrict__ h2, const unsigned int* __restrict__ packed,
    const int* __restrict__ bin_start, const float* __restrict__ s_src,
    const float* __restrict__ s_dst, float* __restrict__ out, int n) {
  __shared__ unsigned int scol[CAP];
  __shared__ int rowbase[RPB + 1];
  __shared__ int cursor[RPB];
  __shared__ int hist[RPB];

  const int bin = blockIdx.x;
  const int start = bin_start[bin];
  const int cnt = bin_start[bin + 1] - start;
  const int t = threadIdx.x;
  const int wave = t >> 6;
  const int lane = t & 63;
  const bool fits = cnt <= CAP;

  if (fits) {
    if (t < RPB) hist[t] = 0;
    __syncthreads();
    for (int i = t; i < cnt; i += 512)
      atomicAdd(&hist[packed[start + i] >> COL_BITS], 1);
    __syncthreads();
    if (t < RPB) cursor[t] = hist[t];
    __syncthreads();
    for (int off = 1; off < RPB; off <<= 1) {
      int y = (t < RPB && t >= off) ? cursor[t - off] : 0;
      __syncthreads();
      if (t < RPB) cursor[t] += y;
      __syncthreads();
    }
    if (t < RPB) rowbase[t + 1] = cursor[t];
    if (t == 0) rowbase[0] = 0;
    __syncthreads();
    if (t < RPB) cursor[t] = rowbase[t];
    __syncthreads();
    for (int i = t; i < cnt; i += 512) {
      unsigned int u = packed[start + i];
      int pos = atomicAdd(&cursor[u >> COL_BITS], 1);
      scol[pos] = u & COL_MASK;
    }
    __syncthreads();
  }

  for (int rr = 0; rr < 16; ++rr) {
    const int lr = wave * 16 + rr;
    const int r = (bin << LOG_RPB) + lr;
    if (r >= n) continue;
    const float sr = s_src[r];
    float acc0 = 0.f, acc1 = 0.f;
    float m = -INFINITY, ssum = 0.f;

    if (fits) {
      const int rs = rowbase[lr];
      const int deg = rowbase[lr + 1] - rs;
      for (int b2 = 0; b2 < deg; b2 += 64) {
        const int rem = deg - b2;
        const bool act = lane < rem;
        int c = act ? (int)scol[rs + b2 + lane] : 0;
        float e = -INFINITY;
        if (act) {
          float ev = sr + s_dst[c];
          e = ev > 0.f ? ev : ALPHA * ev;
        }
        float cm = e;
#pragma unroll
        for (int off = 32; off >= 1; off >>= 1) cm = fmaxf(cm, __shfl_xor(cm, off, 64));
        float m_new = fmaxf(m, cm);
        float scale = __expf(m - m_new);
        acc0 *= scale; acc1 *= scale; ssum *= scale;
        m = m_new;
        float p = act ? __expf(e - m) : 0.f;
        float cs = p;
#pragma unroll
        for (int off = 32; off >= 1; off >>= 1) cs += __shfl_xor(cs, off, 64);
        ssum += cs;
        const int knt = rem < 64 ? rem : 64;
        int k = 0;
        for (; k + 4 <= knt; k += 4) {
          float p0 = rlanef(p, k),     p1 = rlanef(p, k + 1);
          float p2 = rlanef(p, k + 2), p3 = rlanef(p, k + 3);
          int c0 = __builtin_amdgcn_readlane(c, k);
          int c1 = __builtin_amdgcn_readlane(c, k + 1);
          int c2 = __builtin_amdgcn_readlane(c, k + 2);
          int c3 = __builtin_amdgcn_readlane(c, k + 3);
          ushort2 v0 = h2[(size_t)c0 * 64 + lane];
          ushort2 v1 = h2[(size_t)c1 * 64 + lane];
          ushort2 v2 = h2[(size_t)c2 * 64 + lane];
          ushort2 v3 = h2[(size_t)c3 * 64 + lane];
          acc0 += p0 * bf2f(v0.x) + p1 * bf2f(v1.x) + p2 * bf2f(v2.x) + p3 * bf2f(v3.x);
          acc1 += p0 * bf2f(v0.y) + p1 * bf2f(v1.y) + p2 * bf2f(v2.y) + p3 * bf2f(v3.y);
        }
        for (; k < knt; ++k) {
          float pk = rlanef(p, k);
          int ck = __builtin_amdgcn_readlane(c, k);
          ushort2 v = h2[(size_t)ck * 64 + lane];
          acc0 += pk * bf2f(v.x);
          acc1 += pk * bf2f(v.y);
        }
      }
    } else {
      // fallback: bin too large for LDS — filter-scan the bin from global
      for (int b2 = 0; b2 < cnt; b2 += 64) {
        const int i = b2 + lane;
        const bool act = i < cnt;
        unsigned int u = act ? packed[start + i] : 0xFFFFFFFFu;
        const bool match = act && ((int)(u >> COL_BITS) == lr);
        int c = (int)(u & COL_MASK);
        float e = -INFINITY;
        if (match) {
          float ev = sr + s_dst[c];
          e = ev > 0.f ? ev : ALPHA * ev;
        }
        float cm = e;
#pragma unroll
        for (int off = 32; off >= 1; off >>= 1) cm = fmaxf(cm, __shfl_xor(cm, off, 64));
        if (cm == -INFINITY) continue;   // no matching edges in this chunk
        float m_new = fmaxf(m, cm);
        float scale = __expf(m - m_new);
        acc0 *= scale; acc1 *= scale; ssum *= scale;
        m = m_new;
        float p = match ? __expf(e - m) : 0.f;
        float cs = p;
#pragma unroll
        for (int off = 32; off >= 1; off >>= 1) cs += __shfl_xor(cs, off, 64);
        ssum += cs;
        for (int k = 0; k < 64; ++k) {
          float pk = rlanef(p, k);
          if (pk != 0.f) {
            int ck = __builtin_amdgcn_readlane(c, k);
            ushort2 v = h2[(size_t)ck * 64 + lane];
            acc0 += pk * bf2f(v.x);
            acc1 += pk * bf2f(v.y);
          }
        }
      }
    }

    float inv = 1.0f / fmaxf(ssum, EPS);
    acc0 *= inv; acc1 *= inv;
    float o0 = acc0 > 0.f ? acc0 : expm1f(acc0);
    float o1 = acc1 > 0.f ? acc1 : expm1f(acc1);
    *(float2*)&out[(size_t)r * 128 + lane * 2] = make_float2(o0, o1);
  }
}

// ---------------------------------------------------------------------------
static inline size_t align256(size_t v) { return (v + 255) & ~(size_t)255; }

extern "C" void kernel_launch(void* const* d_in, const int* in_sizes, int n_in,
                              void* d_out, int out_size, void* d_ws, size_t ws_size,
                              hipStream_t stream) {
  const float* x   = (const float*)d_in[0];
  const int*   row = (const int*)d_in[1];
  const int*   col = (const int*)d_in[2];
  const float* W   = (const float*)d_in[3];
  const float* a   = (const float*)d_in[4];
  float* out = (float*)d_out;

  const int N = in_sizes[0] / 128;
  const int E = in_sizes[1];
  const int NBIN = (N + RPB - 1) >> LOG_RPB;   // 782 for N=100000 (<=1024)

  char* ws = (char*)d_ws;
  unsigned short* h_bf = (unsigned short*)ws; ws += align256((size_t)N * 128 * 2);
  float* s_src    = (float*)ws;        ws += align256((size_t)N * 4);
  float* s_dst    = (float*)ws;        ws += align256((size_t)N * 4);
  int*   bin_count  = (int*)ws;        ws += align256((size_t)(NBIN + 1) * 4);
  int*   bin_start  = (int*)ws;        ws += align256((size_t)(NBIN + 1) * 4);
  int*   bin_cursor = (int*)ws;        ws += align256((size_t)NBIN * 4);
  unsigned int* packed = (unsigned int*)ws; ws += align256((size_t)E * 4);

  hipMemsetAsync(bin_count, 0, (size_t)(NBIN + 1) * 4, stream);

  dim3 blk(256);
  gemm_scores_kernel<<<dim3((N + 31) / 32), blk, 0, stream>>>(
      x, W, a, h_bf, s_src, s_dst, N);
  binhist_kernel<<<dim3(256), blk, 0, stream>>>(row, bin_count, E, NBIN);
  binscan_kernel<<<dim3(1), blk, 0, stream>>>(bin_count, bin_start, bin_cursor, NBIN);
  binscatter_kernel<<<dim3((E + 4095) / 4096), blk, 0, stream>>>(
      row, col, bin_cursor, packed, E, NBIN);
  attend_bin_kernel<<<dim3(NBIN), dim3(512), 0, stream>>>(
      (const ushort2*)h_bf, packed, bin_start, s_src, s_dst, out, N);
}